// Round 14
// baseline (103.250 us; speedup 1.0000x reference)
//
#include <hip/hip_runtime.h>

#define NROWS 131072
#define DIM 64
#define KCODES 1024
#define MARGIN_DOT 2.5e-4f
#define WIN_FILTER 5e-4f
#define FLAG_CAP 16384
#define OUT_BLOCKS 2048
#define REFINE_BLOCKS 2048

typedef short bf16x8 __attribute__((ext_vector_type(8)));
typedef float f32x4 __attribute__((ext_vector_type(4)));

__device__ __forceinline__ unsigned short f32_to_bf16_rne(float f) {
  unsigned u = __float_as_uint(f);
  u += 0x7FFFu + ((u >> 16) & 1u);
  return (unsigned short)(u >> 16);
}

// load 8 f32, split into bf16 hi/lo planes (RNE both)
__device__ __forceinline__ void cvt_split8(const float* p, bf16x8* hi, bf16x8* lo) {
  float4 f0 = *(const float4*)p;
  float4 f1 = *(const float4*)(p + 4);
  float fv[8] = {f0.x, f0.y, f0.z, f0.w, f1.x, f1.y, f1.z, f1.w};
  union { bf16x8 v; unsigned short u[8]; } H, L;
#pragma unroll
  for (int i = 0; i < 8; i++) {
    unsigned short h = f32_to_bf16_rne(fv[i]);
    float hf = __uint_as_float((unsigned)h << 16);
    H.u[i] = h;
    L.u[i] = f32_to_bf16_rne(fv[i] - hf);
  }
  *hi = H.v;
  *lo = L.v;
}

// ---------------- prep: flag init + enorm64 + split-bf16 emb tiles (UNSWIZZLED) ----------------
// tile ct (16 codes) = 2048 shorts: [0,1024) hi plane, [1024,2048) lo plane,
// linear layout: short_idx = cin*64 + d  (fragments go straight to registers now)
__global__ __launch_bounds__(64) void vq_prep(const float* __restrict__ emb,
                                              double* __restrict__ enorm64,
                                              unsigned short* __restrict__ ehl,
                                              int* __restrict__ flag_count) {
  int k = blockIdx.x;
  int d = threadIdx.x;
  if (k == 0 && d == 0) *flag_count = 0;
  float v = emb[k * 64 + d];
  unsigned short h = f32_to_bf16_rne(v);
  float hf = __uint_as_float((unsigned)h << 16);
  unsigned short l = f32_to_bf16_rne(v - hf);
  int tile = k >> 4, cin = k & 15;
  int sidx = cin * 64 + d;
  ehl[tile * 2048 + sidx] = h;
  ehl[tile * 2048 + 1024 + sidx] = l;
  double s = (double)v * (double)v;
  for (int off = 32; off > 0; off >>= 1) s += __shfl_down(s, off, 64);
  if (d == 0) enorm64[k] = s;
}

// ---------------- pass B: BARRIER-FREE MFMA argmax-dot, direct-to-reg fragments ----------------
// 512 blocks x 4 waves; wave owns 64 rows (4 row-tiles) x all 1024 codes.
// No LDS, no barriers: fragments load L2->VGPR; 4 static buffer sets, prefetch
// distance 2, 4x-unrolled loop (no rotation copies). Waves free-run so one
// wave's fold-VALU overlaps another's MFMA (m114) - kills the R8-R13 phase-
// serialization wall. 24 MFMA + 80 fold-VALU per tile per wave.
__global__ __launch_bounds__(256, 2) void vq_passB(
    const float* __restrict__ z, const unsigned short* __restrict__ ehl,
    float* __restrict__ idx_f, int* __restrict__ flag_count,
    int* __restrict__ flag_rows) {
  const int lane = threadIdx.x & 63;
  const int wv = threadIdx.x >> 6;
  const int lo4 = lane & 15;
  const int hi4 = lane >> 4;
  const int rowb = blockIdx.x * 256 + wv * 64;

  // z fragments: rt row = rowb + rt*16 + lo4; dims ks*32 + hi4*8 .. +7
  bf16x8 zh[4][2], zl[4][2];
#pragma unroll
  for (int rt = 0; rt < 4; rt++) {
    const float* zr = z + (size_t)(rowb + rt * 16 + lo4) * 64 + hi4 * 8;
    cvt_split8(zr, &zh[rt][0], &zl[rt][0]);
    cvt_split8(zr + 32, &zh[rt][1], &zl[rt][1]);
  }

  float m1[4], m2[4];
  int id1[4];
#pragma unroll
  for (int rt = 0; rt < 4; rt++) { m1[rt] = -3.4e38f; m2[rt] = -3.4e38f; id1[rt] = 0; }

  // per-lane fragment base: frags at pb + t*2048 + {0, 32, 1024, 1056} (16B aligned)
  const unsigned short* pb = ehl + lo4 * 64 + hi4 * 8;

#define LOADT(Ph0, Ph1, Pl0, Pl1, t)                       \
  {                                                        \
    const unsigned short* q = pb + (t) * 2048;             \
    Ph0 = *(const bf16x8*)(q);                             \
    Ph1 = *(const bf16x8*)(q + 32);                        \
    Pl0 = *(const bf16x8*)(q + 1024);                      \
    Pl1 = *(const bf16x8*)(q + 1056);                      \
  }

#define PROC(Ph0, Ph1, Pl0, Pl1, t)                                                      \
  {                                                                                      \
    const int cbase = (t) * 16 + hi4 * 4;                                                \
    f32x4 acc[4];                                                                        \
    _Pragma("unroll") for (int rt = 0; rt < 4; rt++) acc[rt] = (f32x4){0.f, 0.f, 0.f, 0.f}; \
    _Pragma("unroll") for (int rt = 0; rt < 4; rt++)                                     \
        acc[rt] = __builtin_amdgcn_mfma_f32_16x16x32_bf16(Ph0, zh[rt][0], acc[rt], 0, 0, 0); \
    _Pragma("unroll") for (int rt = 0; rt < 4; rt++)                                     \
        acc[rt] = __builtin_amdgcn_mfma_f32_16x16x32_bf16(Ph1, zh[rt][1], acc[rt], 0, 0, 0); \
    _Pragma("unroll") for (int rt = 0; rt < 4; rt++)                                     \
        acc[rt] = __builtin_amdgcn_mfma_f32_16x16x32_bf16(Pl0, zh[rt][0], acc[rt], 0, 0, 0); \
    _Pragma("unroll") for (int rt = 0; rt < 4; rt++)                                     \
        acc[rt] = __builtin_amdgcn_mfma_f32_16x16x32_bf16(Pl1, zh[rt][1], acc[rt], 0, 0, 0); \
    _Pragma("unroll") for (int rt = 0; rt < 4; rt++)                                     \
        acc[rt] = __builtin_amdgcn_mfma_f32_16x16x32_bf16(Ph0, zl[rt][0], acc[rt], 0, 0, 0); \
    _Pragma("unroll") for (int rt = 0; rt < 4; rt++)                                     \
        acc[rt] = __builtin_amdgcn_mfma_f32_16x16x32_bf16(Ph1, zl[rt][1], acc[rt], 0, 0, 0); \
    _Pragma("unroll") for (int rt = 0; rt < 4; rt++) {                                   \
      _Pragma("unroll") for (int r = 0; r < 4; r++) {                                    \
        float s = acc[rt][r];                                                            \
        float pm = fminf(m1[rt], s);                                                     \
        m2[rt] = fmaxf(m2[rt], pm);                                                      \
        if (s > m1[rt]) id1[rt] = cbase + r;                                             \
        m1[rt] = fmaxf(m1[rt], s);                                                       \
      }                                                                                  \
    }                                                                                    \
  }

  bf16x8 Ah0, Ah1, Al0, Al1, Bh0, Bh1, Bl0, Bl1;
  bf16x8 Ch0, Ch1, Cl0, Cl1, Dh0, Dh1, Dl0, Dl1;
  LOADT(Ah0, Ah1, Al0, Al1, 0);
  LOADT(Bh0, Bh1, Bl0, Bl1, 1);
  for (int it = 0; it < 16; ++it) {
    const int t = it * 4;
    LOADT(Ch0, Ch1, Cl0, Cl1, t + 2);
    PROC(Ah0, Ah1, Al0, Al1, t);
    LOADT(Dh0, Dh1, Dl0, Dl1, t + 3);
    PROC(Bh0, Bh1, Bl0, Bl1, t + 1);
    {
      const int ta = (t + 4 < 64) ? t + 4 : 63;  // tail: dead loads, never processed
      LOADT(Ah0, Ah1, Al0, Al1, ta);
    }
    PROC(Ch0, Ch1, Cl0, Cl1, t + 2);
    {
      const int tb = (t + 5 < 64) ? t + 5 : 63;
      LOADT(Bh0, Bh1, Bl0, Bl1, tb);
    }
    PROC(Dh0, Dh1, Dl0, Dl1, t + 3);
  }
#undef LOADT
#undef PROC

  // per-row merge over the 4 lane-groups (xor 16, 32) + emit; waves own distinct rows
#pragma unroll
  for (int rt = 0; rt < 4; rt++) {
    float a1 = m1[rt], a2 = m2[rt];
    int ai = id1[rt];
#pragma unroll
    for (int off = 16; off <= 32; off <<= 1) {
      float b1 = __shfl_xor(a1, off, 64);
      float b2 = __shfl_xor(a2, off, 64);
      int bi = __shfl_xor(ai, off, 64);
      float pm = fminf(a1, b1);
      a2 = fmaxf(fmaxf(a2, b2), pm);
      bool take = (b1 > a1) || (b1 == a1 && bi < ai);
      a1 = fmaxf(a1, b1);
      ai = take ? bi : ai;
    }
    if (lane < 16) {
      int row = rowb + rt * 16 + lane;
      idx_f[row] = (float)ai;
      if (a1 - a2 < MARGIN_DOT) {
        int pos = atomicAdd(flag_count, 1);
        if (pos < FLAG_CAP) flag_rows[pos] = row;
      }
    }
  }
}

// ---------------- refine: R5-proven per-row f32 filter + f64 candidate eval ----------------
__global__ __launch_bounds__(256) void vq_refine(const float* __restrict__ z,
                                                 const float* __restrict__ emb,
                                                 const double* __restrict__ enorm64,
                                                 const int* __restrict__ flag_count,
                                                 const int* __restrict__ flag_rows,
                                                 float* __restrict__ idx_f) {
  __shared__ float zs[64];
  __shared__ float smin[256];
  __shared__ int cand[256];
  __shared__ int ccount;
  __shared__ float A32s;
  int cnt = *flag_count;
  if (cnt > FLAG_CAP) cnt = FLAG_CAP;
  const int t = threadIdx.x;
  for (int i = blockIdx.x; i < cnt; i += gridDim.x) {
    int row = flag_rows[i];
    if (t < 64) zs[t] = z[(size_t)row * 64 + t];
    if (t == 0) ccount = 0;
    __syncthreads();
    if (t == 0) {  // sequential f64 row norm -> f32 (proven path)
      double a = 0.0;
      for (int d = 0; d < 64; d++) { double v = (double)zs[d]; a = fma(v, v, a); }
      A32s = (float)a;
    }
    float s_loc[4];
    float my = 3.4e38f;
#pragma unroll
    for (int q = 0; q < 4; q++) {
      int k = t * 4 + q;
      const float4* er = (const float4*)(emb + (size_t)k * 64);
      float dotf = 0.f;
#pragma unroll
      for (int d4 = 0; d4 < 16; d4++) {
        float4 e4 = er[d4];
        float4 zv = ((const float4*)zs)[d4];
        dotf = fmaf(e4.x, zv.x, dotf);
        dotf = fmaf(e4.y, zv.y, dotf);
        dotf = fmaf(e4.z, zv.z, dotf);
        dotf = fmaf(e4.w, zv.w, dotf);
      }
      s_loc[q] = -dotf;
      my = fminf(my, -dotf);
    }
    smin[t] = my;
    __syncthreads();
    for (int s = 128; s > 0; s >>= 1) {
      if (t < s) smin[t] = fminf(smin[t], smin[t + s]);
      __syncthreads();
    }
    float m1 = smin[0];
#pragma unroll
    for (int q = 0; q < 4; q++) {
      if (s_loc[q] - m1 < WIN_FILTER) {
        int p = atomicAdd(&ccount, 1);
        if (p < 256) cand[p] = t * 4 + q;
      }
    }
    __syncthreads();
    int cc = ccount;
    if (cc > 256) cc = 256;
    if (t < 64) {
      float bm = 3.4e38f;
      int bi = 0x7FFFFFFF;
      for (int c = 0; c < cc; c++) {
        int k = cand[c];
        double p = (double)emb[(size_t)k * 64 + t] * (double)zs[t];
        for (int off = 32; off > 0; off >>= 1) p += __shfl_down(p, off, 64);
        if (t == 0) {
          float C = (float)(2.0 * p);
          float B = (float)enorm64[k];
          float T = A32s + B;
          float dist = T - C;
          if (dist < bm || (dist == bm && k < bi)) { bm = dist; bi = k; }
        }
      }
      if (t == 0) idx_f[row] = (float)bi;
    }
    __syncthreads();
  }
}

// ---------------- outputs: quantized_ste + per-block loss partials ----------------
__global__ __launch_bounds__(256) void vq_outputs(
    const float4* __restrict__ z4, const float4* __restrict__ emb4,
    const float* __restrict__ idx_f, float4* __restrict__ out4,
    double* __restrict__ partials) {
  const int tid = threadIdx.x;
  const int g0 = blockIdx.x * 256 + tid;
  double sum = 0.0;
#pragma unroll
  for (int it = 0; it < 4; ++it) {
    int e = g0 + it * (OUT_BLOCKS * 256);
    int row = e >> 4;
    int d4 = e & 15;
    int k = (int)idx_f[row];
    float4 zv = z4[e];
    float4 qv = emb4[k * 16 + d4];
    float dx = qv.x - zv.x, dy = qv.y - zv.y;
    float dz = qv.z - zv.z, dw = qv.w - zv.w;
    float4 o;
    o.x = zv.x + dx; o.y = zv.y + dy; o.z = zv.z + dz; o.w = zv.w + dw;
    out4[e] = o;
    sum += (double)dx * dx + (double)dy * dy + (double)dz * dz + (double)dw * dw;
  }
  for (int off = 32; off > 0; off >>= 1) sum += __shfl_down(sum, off, 64);
  __shared__ double wsum[4];
  if ((tid & 63) == 0) wsum[tid >> 6] = sum;
  __syncthreads();
  if (tid == 0) partials[blockIdx.x] = wsum[0] + wsum[1] + wsum[2] + wsum[3];
}

__global__ __launch_bounds__(256) void vq_final(const double* __restrict__ partials,
                                                float* __restrict__ out_loss) {
  int t = threadIdx.x;
  double s = 0.0;
  for (int i = t; i < OUT_BLOCKS; i += 256) s += partials[i];
  for (int off = 32; off > 0; off >>= 1) s += __shfl_down(s, off, 64);
  __shared__ double wsum[4];
  if ((t & 63) == 0) wsum[t >> 6] = s;
  __syncthreads();
  if (t == 0)
    *out_loss = (float)(1.5 * (wsum[0] + wsum[1] + wsum[2] + wsum[3]) /
                        (double)((size_t)NROWS * DIM));
}

extern "C" void kernel_launch(void* const* d_in, const int* in_sizes, int n_in,
                              void* d_out, int out_size, void* d_ws, size_t ws_size,
                              hipStream_t stream) {
  const float* z = (const float*)d_in[0];
  const float* emb = (const float*)d_in[1];
  float* out = (float*)d_out;
  float* out_q = out;                      // 8388608 floats
  float* out_loss = out + 8388608;         // 1 float
  float* idx_f = out + 8388609;            // 131072 floats

  char* ws = (char*)d_ws;
  double* partials = (double*)ws;                        // [0, 16384)
  double* enorm64 = (double*)(ws + 16384);               // [16384, 24576)
  int* flag_count = (int*)(ws + 24576);                  // 16 B
  unsigned short* ehl = (unsigned short*)(ws + 24592);   // 256 KB split planes
  int* flag_rows = (int*)(ws + 24592 + 262144);          // 64 KB

  vq_prep<<<KCODES, 64, 0, stream>>>(emb, enorm64, ehl, flag_count);
  vq_passB<<<NROWS / 256, 256, 0, stream>>>(z, ehl, idx_f, flag_count, flag_rows);
  vq_refine<<<REFINE_BLOCKS, 256, 0, stream>>>(z, emb, enorm64, flag_count, flag_rows, idx_f);
  vq_outputs<<<OUT_BLOCKS, 256, 0, stream>>>((const float4*)z, (const float4*)emb,
                                             idx_f, (float4*)out_q, partials);
  vq_final<<<1, 256, 0, stream>>>(partials, out_loss);
}